// Round 1
// baseline (2595.933 us; speedup 1.0000x reference)
//
#include <hip/hip_runtime.h>

#define F 128

__global__ void init_out_kernel(float* __restrict__ out, const float* __restrict__ bias,
                                int n_nodes) {
    const float4* b4 = (const float4*)bias;
    float4* o4 = (float4*)out;
    int total = n_nodes * (F / 4);
    for (int i = blockIdx.x * blockDim.x + threadIdx.x; i < total;
         i += gridDim.x * blockDim.x) {
        o4[i] = b4[i & (F / 4 - 1)];
    }
}

// One 64-lane wave per edge. Lane l handles features [2l, 2l+1].
__global__ void edge_scatter_kernel(const int* __restrict__ rows,
                                    const int* __restrict__ cols,
                                    const float* __restrict__ vals,
                                    const float* __restrict__ weight,
                                    float* __restrict__ out, int n_edges) {
    int gid = blockIdx.x * blockDim.x + threadIdx.x;
    int e = gid >> 6;
    if (e >= n_edges) return;
    int lane = threadIdx.x & 63;

    int row = rows[e];
    int col = cols[e];
    float val = vals[e];

    const float2* w2 = (const float2*)(weight + (size_t)col * F);
    float2 w = w2[lane];

    float* o = out + (size_t)row * F + lane * 2;
    unsafeAtomicAdd(o,     val * w.x);
    unsafeAtomicAdd(o + 1, val * w.y);
}

extern "C" void kernel_launch(void* const* d_in, const int* in_sizes, int n_in,
                              void* d_out, int out_size, void* d_ws, size_t ws_size,
                              hipStream_t stream) {
    const int*   rows   = (const int*)d_in[0];
    const int*   cols   = (const int*)d_in[1];
    const float* vals   = (const float*)d_in[2];
    const float* weight = (const float*)d_in[3];
    const float* bias   = (const float*)d_in[4];
    float* out = (float*)d_out;

    int n_edges = in_sizes[0];
    int n_nodes = out_size / F;

    // out = broadcast(bias)
    init_out_kernel<<<2048, 256, 0, stream>>>(out, bias, n_nodes);

    // out[row] += val * weight[col]
    const int block = 256;
    const int waves_per_block = block / 64;
    int grid = (n_edges + waves_per_block - 1) / waves_per_block;
    edge_scatter_kernel<<<grid, block, 0, stream>>>(rows, cols, vals, weight, out,
                                                    n_edges);
}

// Round 2
// 631.938 us; speedup vs baseline: 4.1079x; 4.1079x over previous
//
#include <hip/hip_runtime.h>

#define F 128
#define SCAN_CHUNK 512
#define SCAN_THREADS 256

// ---------------- CSR-build + segment-sum path ----------------

__global__ void zero_kernel(int* __restrict__ p, int n) {
    int stride = gridDim.x * blockDim.x;
    for (int i = blockIdx.x * blockDim.x + threadIdx.x; i < n; i += stride) p[i] = 0;
}

__global__ void hist_kernel(const int* __restrict__ rows, int* __restrict__ counts,
                            int n_edges) {
    int stride = gridDim.x * blockDim.x;
    for (int i = blockIdx.x * blockDim.x + threadIdx.x; i < n_edges; i += stride)
        atomicAdd(&counts[rows[i]], 1);
}

// per-block sums of SCAN_CHUNK counts
__global__ void blocksum_kernel(const int* __restrict__ counts, int* __restrict__ partial,
                                int n) {
    __shared__ int lds[SCAN_THREADS];
    int t = threadIdx.x;
    int i0 = blockIdx.x * SCAN_CHUNK + t * 2;
    int s = 0;
    if (i0 < n) s += counts[i0];
    if (i0 + 1 < n) s += counts[i0 + 1];
    lds[t] = s;
    __syncthreads();
    for (int off = SCAN_THREADS / 2; off > 0; off >>= 1) {
        if (t < off) lds[t] += lds[t + off];
        __syncthreads();
    }
    if (t == 0) partial[blockIdx.x] = lds[0];
}

// single-block exclusive scan of the partials (nb <= SCAN_THREADS)
__global__ void scanpartial_kernel(const int* __restrict__ partial,
                                   int* __restrict__ partialscan, int nb) {
    __shared__ int lds[SCAN_THREADS];
    int t = threadIdx.x;
    int v = (t < nb) ? partial[t] : 0;
    lds[t] = v;
    __syncthreads();
    for (int off = 1; off < SCAN_THREADS; off <<= 1) {
        int add = (t >= off) ? lds[t - off] : 0;
        __syncthreads();
        lds[t] += add;
        __syncthreads();
    }
    if (t < nb) partialscan[t] = lds[t] - v;  // exclusive
}

// per-chunk exclusive scan + base -> offs, cursor
__global__ void blockscan_kernel(const int* __restrict__ counts,
                                 const int* __restrict__ partialscan,
                                 int* __restrict__ offs, int* __restrict__ cursor, int n) {
    __shared__ int lds[SCAN_THREADS];
    int t = threadIdx.x;
    int i0 = blockIdx.x * SCAN_CHUNK + t * 2;
    int c0 = (i0 < n) ? counts[i0] : 0;
    int c1 = (i0 + 1 < n) ? counts[i0 + 1] : 0;
    int ts = c0 + c1;
    lds[t] = ts;
    __syncthreads();
    for (int off = 1; off < SCAN_THREADS; off <<= 1) {
        int add = (t >= off) ? lds[t - off] : 0;
        __syncthreads();
        lds[t] += add;
        __syncthreads();
    }
    int excl = lds[t] - ts + partialscan[blockIdx.x];
    if (i0 < n)     { offs[i0] = excl;          cursor[i0] = excl; }
    if (i0 + 1 < n) { offs[i0 + 1] = excl + c0; cursor[i0 + 1] = excl + c0; }
}

__global__ void scatter_kernel(const int* __restrict__ rows, const int* __restrict__ cols,
                               const float* __restrict__ vals, int* __restrict__ cursor,
                               int* __restrict__ e_col, float* __restrict__ e_val,
                               int n_edges) {
    int stride = gridDim.x * blockDim.x;
    for (int i = blockIdx.x * blockDim.x + threadIdx.x; i < n_edges; i += stride) {
        int r = rows[i];
        int p = atomicAdd(&cursor[r], 1);
        e_col[p] = cols[i];
        e_val[p] = vals[i];
    }
}

// one 64-lane wave per row; lane l accumulates features [2l, 2l+1]
__global__ void rowacc_kernel(const int* __restrict__ offs, const int* __restrict__ counts,
                              const int* __restrict__ e_col, const float* __restrict__ e_val,
                              const float* __restrict__ weight, const float* __restrict__ bias,
                              float* __restrict__ out, int n_nodes) {
    int wid = (blockIdx.x * blockDim.x + threadIdx.x) >> 6;
    if (wid >= n_nodes) return;
    int lane = threadIdx.x & 63;

    int e = offs[wid];
    int end = e + counts[wid];

    float ax = 0.f, ay = 0.f;
    for (; e + 4 <= end; e += 4) {
        int c0 = e_col[e], c1 = e_col[e + 1], c2 = e_col[e + 2], c3 = e_col[e + 3];
        float v0 = e_val[e], v1 = e_val[e + 1], v2 = e_val[e + 2], v3 = e_val[e + 3];
        float2 w0 = ((const float2*)(weight + (size_t)c0 * F))[lane];
        float2 w1 = ((const float2*)(weight + (size_t)c1 * F))[lane];
        float2 w2 = ((const float2*)(weight + (size_t)c2 * F))[lane];
        float2 w3 = ((const float2*)(weight + (size_t)c3 * F))[lane];
        ax += v0 * w0.x + v1 * w1.x + v2 * w2.x + v3 * w3.x;
        ay += v0 * w0.y + v1 * w1.y + v2 * w2.y + v3 * w3.y;
    }
    for (; e < end; ++e) {
        int c = e_col[e];
        float v = e_val[e];
        float2 w = ((const float2*)(weight + (size_t)c * F))[lane];
        ax += v * w.x;
        ay += v * w.y;
    }
    float2 b = ((const float2*)bias)[lane];
    float2 r;
    r.x = ax + b.x;
    r.y = ay + b.y;
    ((float2*)(out + (size_t)wid * F))[lane] = r;
}

// ---------------- fallback: round-1 atomic path ----------------

__global__ void init_out_kernel(float* __restrict__ out, const float* __restrict__ bias,
                                int n_nodes) {
    const float4* b4 = (const float4*)bias;
    float4* o4 = (float4*)out;
    int total = n_nodes * (F / 4);
    for (int i = blockIdx.x * blockDim.x + threadIdx.x; i < total;
         i += gridDim.x * blockDim.x)
        o4[i] = b4[i & (F / 4 - 1)];
}

__global__ void edge_scatter_kernel(const int* __restrict__ rows,
                                    const int* __restrict__ cols,
                                    const float* __restrict__ vals,
                                    const float* __restrict__ weight,
                                    float* __restrict__ out, int n_edges) {
    int e = (blockIdx.x * blockDim.x + threadIdx.x) >> 6;
    if (e >= n_edges) return;
    int lane = threadIdx.x & 63;
    int row = rows[e];
    int col = cols[e];
    float val = vals[e];
    float2 w = ((const float2*)(weight + (size_t)col * F))[lane];
    float* o = out + (size_t)row * F + lane * 2;
    unsafeAtomicAdd(o, val * w.x);
    unsafeAtomicAdd(o + 1, val * w.y);
}

extern "C" void kernel_launch(void* const* d_in, const int* in_sizes, int n_in,
                              void* d_out, int out_size, void* d_ws, size_t ws_size,
                              hipStream_t stream) {
    const int*   rows   = (const int*)d_in[0];
    const int*   cols   = (const int*)d_in[1];
    const float* vals   = (const float*)d_in[2];
    const float* weight = (const float*)d_in[3];
    const float* bias   = (const float*)d_in[4];
    float* out = (float*)d_out;

    int n_edges = in_sizes[0];
    int n_nodes = out_size / F;

    int nb = (n_nodes + SCAN_CHUNK - 1) / SCAN_CHUNK;  // scan blocks

    // ws layout (all int32-sized)
    size_t need = ((size_t)3 * n_nodes + 2 * SCAN_THREADS + 2 * (size_t)n_edges) * 4;

    if (ws_size < need || nb > SCAN_THREADS) {
        // fallback: atomic scatter (round-1 path)
        init_out_kernel<<<2048, 256, 0, stream>>>(out, bias, n_nodes);
        int grid = (n_edges + 3) / 4;
        edge_scatter_kernel<<<grid, 256, 0, stream>>>(rows, cols, vals, weight, out,
                                                      n_edges);
        return;
    }

    int* counts      = (int*)d_ws;
    int* offs        = counts + n_nodes;
    int* cursor      = offs + n_nodes;
    int* partial     = cursor + n_nodes;
    int* partialscan = partial + SCAN_THREADS;
    int* e_col       = partialscan + SCAN_THREADS;
    float* e_val     = (float*)(e_col + n_edges);

    zero_kernel<<<(n_nodes + 255) / 256, 256, 0, stream>>>(counts, n_nodes);
    hist_kernel<<<2048, 256, 0, stream>>>(rows, counts, n_edges);
    blocksum_kernel<<<nb, SCAN_THREADS, 0, stream>>>(counts, partial, n_nodes);
    scanpartial_kernel<<<1, SCAN_THREADS, 0, stream>>>(partial, partialscan, nb);
    blockscan_kernel<<<nb, SCAN_THREADS, 0, stream>>>(counts, partialscan, offs, cursor,
                                                      n_nodes);
    scatter_kernel<<<2048, 256, 0, stream>>>(rows, cols, vals, cursor, e_col, e_val,
                                             n_edges);

    int waves_per_block = 256 / 64;
    int grid = (n_nodes + waves_per_block - 1) / waves_per_block;
    rowacc_kernel<<<grid, 256, 0, stream>>>(offs, counts, e_col, e_val, weight, bias, out,
                                            n_nodes);
}